// Round 6
// baseline (288.761 us; speedup 1.0000x reference)
//
#include <hip/hip_runtime.h>
#include <math.h>

// Problem constants (B=8, S=2048, D=512)
#define B_ 8
#define S_ 2048
#define D_ 512
#define KTOP 204                      // int(2048*0.1)
#define QK_SCALE 0.044194173824159216f // 1/sqrt(512)

typedef short bfrag8 __attribute__((ext_vector_type(8)));  // 8 bf16 (4 VGPRs)
typedef float facc4 __attribute__((ext_vector_type(4)));   // MFMA accumulator

// ---------- helpers ----------
__device__ __forceinline__ unsigned short f2bf(float f) {
  unsigned u = __float_as_uint(f);
  u += 0x7FFFu + ((u >> 16) & 1);   // RNE
  return (unsigned short)(u >> 16);
}

// order-preserving map: descending float order == descending uint order
__device__ __forceinline__ unsigned fkey(float f) {
  unsigned b = __float_as_uint(f);
  return (b & 0x80000000u) ? ~b : (b | 0x80000000u);
}
__device__ __forceinline__ float keyfloat(unsigned k) {
  unsigned b = (k & 0x80000000u) ? (k & 0x7FFFFFFFu) : ~k;
  return __uint_as_float(b);
}

__device__ __forceinline__ void load16(const unsigned short* g, unsigned short* l) {
  __builtin_amdgcn_global_load_lds(
      (const __attribute__((address_space(1))) void*)g,
      (__attribute__((address_space(3))) void*)l, 16, 0, 0);
}

// ---------- fp32 -> bf16 convert, Q and K in one launch ----------
__global__ __launch_bounds__(256) void cvt_qk(const float* __restrict__ Q,
                                              const float* __restrict__ K,
                                              unsigned short* __restrict__ Qb,
                                              unsigned short* __restrict__ Kb) {
  const float* in = blockIdx.y ? K : Q;
  unsigned short* out = blockIdx.y ? Kb : Qb;
  int i = (blockIdx.x * 256 + threadIdx.x) * 4;
  float4 v = *(const float4*)(in + i);
  ushort4 o;
  o.x = f2bf(v.x); o.y = f2bf(v.y); o.z = f2bf(v.z); o.w = f2bf(v.w);
  *(ushort4*)(out + i) = o;
}

// ---------- V [b][k][d] fp32 -> VT [b][d][k] bf16 ----------
__global__ __launch_bounds__(256) void transpose_v(const float* __restrict__ V,
                                                   unsigned short* __restrict__ VT) {
  __shared__ float tile[32][33];
  int b = blockIdx.z;
  int d0 = blockIdx.x * 32, k0 = blockIdx.y * 32;
  const float* Vb = V + (size_t)b * S_ * D_;
  unsigned short* VTb = VT + (size_t)b * D_ * S_;
  int c = threadIdx.x & 31, r = threadIdx.x >> 5;
#pragma unroll
  for (int rr = 0; rr < 32; rr += 8)
    tile[r + rr][c] = Vb[(size_t)(k0 + r + rr) * D_ + d0 + c];
  __syncthreads();
#pragma unroll
  for (int rr = 0; rr < 32; rr += 8)
    VTb[(size_t)(d0 + r + rr) * S_ + k0 + c] = f2bf(tile[c][r + rr]);
}

// ---------- batched BT-layout MFMA GEMM, TRANSPOSED OUTPUT ----------
// R7 change (both gemm variants):
//  (a) operand swap at the call site + transposed C-write: kernel computes
//      T[m][n] = scale * sum_k A[m][k]*Bm[n][k] and stores C[n][m] = T[m][n].
//      The MFMA fragment's 4 per-thread rows (quad*4+r, along m) are then the
//      FAST axis of C -> each thread stores facc4 (dwordx4) instead of 4
//      column-strided dwords: 64 scalar stores -> 16 vector stores per thread.
//  (b) LDS slot swizzle (both-sides): staging source col = ((tid&3)^(srow&3))*8
//      with linear LDS dest (global_load_lds requirement); fragment read slot =
//      quad ^ (l15&3). Kills the 8-way bank conflict of 64B-row b128 reads
//      (banks {0,16} x8 lanes -> {0,8,20,28} x4 lanes = 4-way).
// gemm1 variant: grid (16,16,8); bz=j&7 pins batch to XCD (Qb[b]+Kb[b]=4MB=L2).
__global__ __launch_bounds__(256) void gemm_qk(
    const unsigned short* __restrict__ A, int lda, long long astr,
    const unsigned short* __restrict__ Bm, int ldb, long long bstr,
    float* __restrict__ C, int ldc, long long cstr,
    int kdim, float scale) {
  const unsigned j = blockIdx.x + 16u * blockIdx.y + 256u * blockIdx.z;
  const unsigned bz = j & 7u;           // batch == XCD residue
  const unsigned q = j >> 3;            // [0,256)
  const unsigned bm = q & 15u;          // m-tile (k-dim of scores)
  const unsigned bn = q >> 4;           // n-tile (q-dim of scores)

  __shared__ unsigned short smA[128 * 32];
  __shared__ unsigned short smB[128 * 32];
  const int tid = threadIdx.x;
  const int wave = tid >> 6, lane = tid & 63;
  const int quad = lane >> 4, l15 = lane & 15;
  const unsigned short* Ab = A + (long long)bz * astr + (size_t)(bm * 128) * lda;
  const unsigned short* Bb = Bm + (long long)bz * bstr + (size_t)(bn * 128) * ldb;
  const int srow = tid >> 2;                      // staging row 0..63
  const int scol = ((tid & 3) ^ (srow & 3)) * 8;  // swizzled source col (elements)
  unsigned short* lA0 = smA + wave * 512;
  unsigned short* lA1 = smA + 2048 + wave * 512;
  unsigned short* lB0 = smB + wave * 512;
  unsigned short* lB1 = smB + 2048 + wave * 512;
  const int mrow = 64 * (wave >> 1);
  const int nrow = 64 * (wave & 1);
  const int rsw = (quad ^ (l15 & 3)) * 8;         // swizzled read slot (elements)

  facc4 acc[4][4];
  const facc4 fzero = {0.f, 0.f, 0.f, 0.f};
#pragma unroll
  for (int i = 0; i < 4; ++i)
#pragma unroll
    for (int j2 = 0; j2 < 4; ++j2) acc[i][j2] = fzero;

  for (int k0 = 0; k0 < kdim; k0 += 32) {
    __syncthreads();
    load16(Ab + (size_t)srow * lda + k0 + scol, lA0);
    load16(Ab + (size_t)(srow + 64) * lda + k0 + scol, lA1);
    load16(Bb + (size_t)srow * ldb + k0 + scol, lB0);
    load16(Bb + (size_t)(srow + 64) * ldb + k0 + scol, lB1);
    __syncthreads();
    bfrag8 af[4], bq[4];
#pragma unroll
    for (int i = 0; i < 4; ++i)
      af[i] = *(const bfrag8*)(smA + (mrow + 16 * i + l15) * 32 + rsw);
#pragma unroll
    for (int j2 = 0; j2 < 4; ++j2)
      bq[j2] = *(const bfrag8*)(smB + (nrow + 16 * j2 + l15) * 32 + rsw);
#pragma unroll
    for (int i = 0; i < 4; ++i)
#pragma unroll
      for (int j2 = 0; j2 < 4; ++j2)
        acc[i][j2] = __builtin_amdgcn_mfma_f32_16x16x32_bf16(af[i], bq[j2], acc[i][j2], 0, 0, 0);
  }

  float* Cb = C + (long long)bz * cstr;
  const int mg = bm * 128 + mrow;   // fast axis of C (k of scores)
  const int ng = bn * 128 + nrow;   // slow axis of C (q of scores)
#pragma unroll
  for (int i = 0; i < 4; ++i)
#pragma unroll
    for (int j2 = 0; j2 < 4; ++j2) {
      facc4 v = acc[i][j2] * scale;
      *(facc4*)(Cb + (size_t)(ng + 16 * j2 + l15) * ldc + mg + 16 * i + quad * 4) = v;
    }
}

// gemm2 variant: grid (4,16,8); bz=j&7 (batch pins to XCD). A=VT (m over d,
// 4 tiles, fastest), B=attn (n over q, 16 tiles): the 4 d-blocks sharing one
// 512KB attn B-tile run back-to-back on the same XCD (fetched from HBM once).
__global__ __launch_bounds__(256) void gemm_pv(
    const unsigned short* __restrict__ A, int lda, long long astr,
    const unsigned short* __restrict__ Bm, int ldb, long long bstr,
    float* __restrict__ C, int ldc, long long cstr,
    int kdim, float scale) {
  const unsigned j = blockIdx.x + 4u * blockIdx.y + 64u * blockIdx.z;
  const unsigned bz = j & 7u;           // batch == XCD residue
  const unsigned q = j >> 3;            // [0,64)
  const unsigned bm = q & 3u;           // m-tile over d (fastest)
  const unsigned bn = q >> 2;           // n-tile over q [0,16)

  __shared__ unsigned short smA[128 * 32];
  __shared__ unsigned short smB[128 * 32];
  const int tid = threadIdx.x;
  const int wave = tid >> 6, lane = tid & 63;
  const int quad = lane >> 4, l15 = lane & 15;
  const unsigned short* Ab = A + (long long)bz * astr + (size_t)(bm * 128) * lda;
  const unsigned short* Bb = Bm + (long long)bz * bstr + (size_t)(bn * 128) * ldb;
  const int srow = tid >> 2;
  const int scol = ((tid & 3) ^ (srow & 3)) * 8;  // swizzled source col
  unsigned short* lA0 = smA + wave * 512;
  unsigned short* lA1 = smA + 2048 + wave * 512;
  unsigned short* lB0 = smB + wave * 512;
  unsigned short* lB1 = smB + 2048 + wave * 512;
  const int mrow = 64 * (wave >> 1);
  const int nrow = 64 * (wave & 1);
  const int rsw = (quad ^ (l15 & 3)) * 8;         // swizzled read slot

  facc4 acc[4][4];
  const facc4 fzero = {0.f, 0.f, 0.f, 0.f};
#pragma unroll
  for (int i = 0; i < 4; ++i)
#pragma unroll
    for (int j2 = 0; j2 < 4; ++j2) acc[i][j2] = fzero;

  for (int k0 = 0; k0 < kdim; k0 += 32) {
    __syncthreads();
    load16(Ab + (size_t)srow * lda + k0 + scol, lA0);
    load16(Ab + (size_t)(srow + 64) * lda + k0 + scol, lA1);
    load16(Bb + (size_t)srow * ldb + k0 + scol, lB0);
    load16(Bb + (size_t)(srow + 64) * ldb + k0 + scol, lB1);
    __syncthreads();
    bfrag8 af[4], bq[4];
#pragma unroll
    for (int i = 0; i < 4; ++i)
      af[i] = *(const bfrag8*)(smA + (mrow + 16 * i + l15) * 32 + rsw);
#pragma unroll
    for (int j2 = 0; j2 < 4; ++j2)
      bq[j2] = *(const bfrag8*)(smB + (nrow + 16 * j2 + l15) * 32 + rsw);
#pragma unroll
    for (int i = 0; i < 4; ++i)
#pragma unroll
      for (int j2 = 0; j2 < 4; ++j2)
        acc[i][j2] = __builtin_amdgcn_mfma_f32_16x16x32_bf16(af[i], bq[j2], acc[i][j2], 0, 0, 0);
  }

  float* Cb = C + (long long)bz * cstr;
  const int mg = bm * 128 + mrow;   // fast axis of C (d of out)
  const int ng = bn * 128 + nrow;   // slow axis of C (q of out)
#pragma unroll
  for (int i = 0; i < 4; ++i)
#pragma unroll
    for (int j2 = 0; j2 < 4; ++j2) {
      facc4 v = acc[i][j2] * scale;
      *(facc4*)(Cb + (size_t)(ng + 16 * j2 + l15) * ldc + mg + 16 * i + quad * 4) = v;
    }
}

// ---------- 256-bin radix-select step (per-wave histogram already counted) ----------
// bins[256]: counts. Finds digit d* s.t. count(digit > d*) < krem <= count(digit >= d*).
// Returns d*; *krem_out = krem - count(digit > d*)  (rank within the d* bin).
// If no crossing exists (total count < krem), returns 0 with *krem_out = 0.
__device__ __forceinline__ unsigned sel256(const unsigned* bins, int lane,
                                           unsigned krem, unsigned* krem_out) {
  const uint4 b = *(const uint4*)(bins + lane * 4);
  const unsigned s = b.x + b.y + b.z + b.w;
  unsigned t = s;
#pragma unroll
  for (int off = 1; off < 64; off <<= 1) {
    unsigned u = (unsigned)__shfl_down((int)t, off);
    t += (lane + off < 64) ? u : 0u;
  }
  const unsigned texcl = t - s;           // suffix over lanes > lane
  const unsigned c3 = texcl + b.w;        // count(digit >= lane*4+3)
  const unsigned c2 = c3 + b.z;
  const unsigned c1 = c2 + b.y;
  const unsigned c0 = c1 + b.x;
  unsigned pack = 0;                      // nonzero in at most one lane
  if (c0 >= krem && c1 < krem)    pack = ((krem - c1) << 8) | (lane * 4 + 0);
  if (c1 >= krem && c2 < krem)    pack = ((krem - c2) << 8) | (lane * 4 + 1);
  if (c2 >= krem && c3 < krem)    pack = ((krem - c3) << 8) | (lane * 4 + 2);
  if (c3 >= krem && texcl < krem) pack = ((krem - texcl) << 8) | (lane * 4 + 3);
#pragma unroll
  for (int off = 1; off < 64; off <<= 1)
    pack |= (unsigned)__shfl_xor((int)pack, off);
  *krem_out = pack >> 8;
  return pack & 255u;
}

// ---------- per-row exact top-204 + softmax-of-sparse; one WAVE per row ----------
// R6 (kept verbatim — proven: conflicts gone, ~44us): quantile-digit select,
// losers not counted. Pass-1 digit t=(key>>16)-0xBF00 counts only t in [1,255];
// scores < ~0.5 can't be top-204 when >=204 elements have t>=1 (N(0,1): ~632).
// d1 in [1,254] pins the key's top 16 bits; 2 more 8-bit passes finish. Any
// degenerate case (d1==0 no-crossing, or clamp-top d1==255) -> full exact
// 4-pass radix fallback (wave-uniform, never taken for this data).
__global__ __launch_bounds__(256) void topk_softmax(float* __restrict__ scores) {
  __shared__ unsigned binsAll[4][256];    // 1KB per wave
  const int tid = threadIdx.x;
  const int wave = tid >> 6, lane = tid & 63;
  const long long row = (long long)blockIdx.x * 4 + wave;
  float* srow = scores + row * 2048;
  unsigned* bins = binsAll[wave];

  unsigned k[32];
#pragma unroll
  for (int c = 0; c < 4; ++c) {
    float4 a = *(const float4*)(srow + c * 512 + lane * 8);
    float4 b = *(const float4*)(srow + c * 512 + lane * 8 + 4);
    k[c * 8 + 0] = fkey(a.x); k[c * 8 + 1] = fkey(a.y);
    k[c * 8 + 2] = fkey(a.z); k[c * 8 + 3] = fkey(a.w);
    k[c * 8 + 4] = fkey(b.x); k[c * 8 + 5] = fkey(b.y);
    k[c * 8 + 6] = fkey(b.z); k[c * 8 + 7] = fkey(b.w);
  }

  // row max (for softmax shift m = max(max_score, 0))
  unsigned kmax = 0;
#pragma unroll
  for (int i = 0; i < 32; ++i) kmax = max(kmax, k[i]);
#pragma unroll
  for (int off = 1; off < 64; off <<= 1)
    kmax = max(kmax, (unsigned)__shfl_xor((int)kmax, off));
  const float m = fmaxf(keyfloat(kmax), 0.f);

  // ---- pass 1: quantile digit t = (key>>16) - 0xBF00; count only t in [1,255] ----
  {
    uint4 z; z.x = 0; z.y = 0; z.z = 0; z.w = 0;
    *(uint4*)(bins + lane * 4) = z;
  }
#pragma unroll
  for (int i = 0; i < 32; ++i) {
    const int t = (int)(k[i] >> 16) - 0xBF00;
    if (t >= 1) atomicAdd(&bins[min(t, 255)], 1u);
  }
  unsigned krem;
  const unsigned d1 = sel256(bins, lane, KTOP, &krem);

  unsigned tkey;
  if (d1 >= 1u && d1 <= 254u) {
    // common path: key's top 16 bits are exactly 0xBF00+d1 (unclamped digit)
    const unsigned top16 = 0xBF00u + d1;
    // ---- pass 2: bits[15:8] among class (key>>16)==top16 ----
    { uint4 z; z.x = 0; z.y = 0; z.z = 0; z.w = 0; *(uint4*)(bins + lane * 4) = z; }
#pragma unroll
    for (int i = 0; i < 32; ++i)
      if ((k[i] >> 16) == top16) atomicAdd(&bins[(k[i] >> 8) & 255u], 1u);
    const unsigned b1 = sel256(bins, lane, krem, &krem);
    const unsigned top24 = (top16 << 8) | b1;
    // ---- pass 3: bits[7:0] among class (key>>8)==top24 ----
    { uint4 z; z.x = 0; z.y = 0; z.z = 0; z.w = 0; *(uint4*)(bins + lane * 4) = z; }
#pragma unroll
    for (int i = 0; i < 32; ++i)
      if ((k[i] >> 8) == top24) atomicAdd(&bins[k[i] & 255u], 1u);
    const unsigned b0 = sel256(bins, lane, krem, &krem);
    tkey = (top24 << 8) | b0;
  } else {
    // fallback: full exact 4-pass 8-bit radix from scratch. Never taken here.
    krem = KTOP;
    unsigned prefix = 0, mmask = 0;
    for (int shift = 24; shift >= 0; shift -= 8) {
      { uint4 z; z.x = 0; z.y = 0; z.z = 0; z.w = 0; *(uint4*)(bins + lane * 4) = z; }
#pragma unroll
      for (int i = 0; i < 32; ++i)
        if ((k[i] & mmask) == prefix) atomicAdd(&bins[(k[i] >> shift) & 255u], 1u);
      const unsigned dig = sel256(bins, lane, krem, &krem);
      prefix |= dig << shift;
      mmask |= 0xFFu << shift;
    }
    tkey = prefix;
  }

  // tie-break: accept the krem lowest-index elements with key == tkey.
  // cut = global index of the last accepted tie.
  unsigned cut;
  {
    unsigned tiem = 0;
#pragma unroll
    for (int i = 0; i < 32; ++i)
      if (k[i] == tkey) tiem |= 1u << i;
    unsigned need = krem;
    for (;;) {
      unsigned myidx = 0xFFFFFFFFu;
      if (tiem) {
        int i = __ffs((int)tiem) - 1;       // lowest i = smallest global idx in lane
        myidx = ((unsigned)(i >> 3)) * 512u + (unsigned)lane * 8u + (unsigned)(i & 7);
      }
      unsigned minidx = myidx;
#pragma unroll
      for (int off = 1; off < 64; off <<= 1)
        minidx = min(minidx, (unsigned)__shfl_xor((int)minidx, off));
      if (--need == 0 || minidx == 0xFFFFFFFFu) { cut = minidx; break; }
      if (myidx == minidx) tiem &= tiem - 1; // consume in owning lane
    }
  }

  // weights: exp(s-m) if selected, exp(-m) otherwise; Z = sum of all weights
  const float eqw = __expf(keyfloat(tkey) - m);
  const float base = __expf(-m);
  float zsum = 0.f;
#pragma unroll
  for (int i = 0; i < 32; ++i) {
    const unsigned key = k[i];
    const unsigned idx = ((unsigned)(i >> 3)) * 512u + (unsigned)lane * 8u + (unsigned)(i & 7);
    float w;
    if (key > tkey) w = __expf(keyfloat(key) - m);
    else w = (key == tkey && idx <= cut) ? eqw : base;
    zsum += w;
    k[i] = __float_as_uint(w);              // stash unnormalized weight
  }
#pragma unroll
  for (int off = 1; off < 64; off <<= 1) zsum += __shfl_xor(zsum, off);
  const float invZ = 1.f / zsum;

  // attn row (bf16) reuses the front 4KB of this row's 8KB score slot
  unsigned short* arow = (unsigned short*)scores + row * 4096;
#pragma unroll
  for (int c = 0; c < 4; ++c) {
    union { unsigned short u[8]; int4 v4; } pk;
#pragma unroll
    for (int j = 0; j < 8; ++j)
      pk.u[j] = f2bf(__uint_as_float(k[c * 8 + j]) * invZ);
    *(int4*)(arow + c * 512 + lane * 8) = pk.v4;
  }
}

// ---------- launch ----------
// ws layout (bytes): Qb[0,16MB) Kb[16,32MB) VT[32,48MB) scores/attn[48,176MB)
extern "C" void kernel_launch(void* const* d_in, const int* in_sizes, int n_in,
                              void* d_out, int out_size, void* d_ws, size_t ws_size,
                              hipStream_t stream) {
  const float* Q = (const float*)d_in[0];
  const float* K = (const float*)d_in[1];
  const float* V = (const float*)d_in[2];
  float* out = (float*)d_out;
  char* ws = (char*)d_ws;
  unsigned short* Qb = (unsigned short*)(ws);
  unsigned short* Kb = (unsigned short*)(ws + ((size_t)16 << 20));
  unsigned short* VT = (unsigned short*)(ws + ((size_t)32 << 20));
  float* scores = (float*)(ws + ((size_t)48 << 20));

  const int nel = B_ * S_ * D_;  // 8388608
  cvt_qk<<<dim3(nel / 1024, 2), 256, 0, stream>>>(Q, K, Qb, Kb);
  transpose_v<<<dim3(D_ / 32, S_ / 32, B_), 256, 0, stream>>>(V, VT);
  // gemm_qk computes T[k][q] = K[k]·Q[q]*scale, stores scores[q][k] (transposed
  // write -> per-thread float4 along k). A=Kb (m over k), B=Qb (n over q).
  gemm_qk<<<dim3(S_ / 128, S_ / 128, B_), 256, 0, stream>>>(
      Kb, D_, (long long)S_ * D_, Qb, D_, (long long)S_ * D_,
      scores, S_, (long long)S_ * S_, D_, QK_SCALE);
  topk_softmax<<<B_ * S_ / 4, 256, 0, stream>>>(scores);
  // gemm_pv computes T[d][q] = VT[d]·attn[q], stores out[q][d] (transposed
  // write -> per-thread float4 along d). A=VT (m over d), B=attn (n over q,
  // row pitch 4096 bf16 = 8KB slots).
  gemm_pv<<<dim3(D_ / 128, S_ / 128, B_), 256, 0, stream>>>(
      VT, S_, (long long)D_ * S_,
      (const unsigned short*)scores, 4096, (long long)S_ * 4096,
      out, D_, (long long)S_ * D_, S_, 1.0f);
}

// Round 7
// 286.023 us; speedup vs baseline: 1.0096x; 1.0096x over previous
//
#include <hip/hip_runtime.h>
#include <math.h>

// Problem constants (B=8, S=2048, D=512)
#define B_ 8
#define S_ 2048
#define D_ 512
#define KTOP 204                      // int(2048*0.1)
#define QK_SCALE 0.044194173824159216f // 1/sqrt(512)

typedef short bfrag8 __attribute__((ext_vector_type(8)));  // 8 bf16 (4 VGPRs)
typedef float facc4 __attribute__((ext_vector_type(4)));   // MFMA accumulator

// ---------- helpers ----------
__device__ __forceinline__ unsigned short f2bf(float f) {
  unsigned u = __float_as_uint(f);
  u += 0x7FFFu + ((u >> 16) & 1);   // RNE
  return (unsigned short)(u >> 16);
}

// order-preserving map: descending float order == descending uint order
__device__ __forceinline__ unsigned fkey(float f) {
  unsigned b = __float_as_uint(f);
  return (b & 0x80000000u) ? ~b : (b | 0x80000000u);
}
__device__ __forceinline__ float keyfloat(unsigned k) {
  unsigned b = (k & 0x80000000u) ? (k & 0x7FFFFFFFu) : ~k;
  return __uint_as_float(b);
}

__device__ __forceinline__ void load16(const unsigned short* g, unsigned short* l) {
  __builtin_amdgcn_global_load_lds(
      (const __attribute__((address_space(1))) void*)g,
      (__attribute__((address_space(3))) void*)l, 16, 0, 0);
}

// ---------- fp32 -> bf16 convert, Q and K in one launch ----------
__global__ __launch_bounds__(256) void cvt_qk(const float* __restrict__ Q,
                                              const float* __restrict__ K,
                                              unsigned short* __restrict__ Qb,
                                              unsigned short* __restrict__ Kb) {
  const float* in = blockIdx.y ? K : Q;
  unsigned short* out = blockIdx.y ? Kb : Qb;
  int i = (blockIdx.x * 256 + threadIdx.x) * 4;
  float4 v = *(const float4*)(in + i);
  ushort4 o;
  o.x = f2bf(v.x); o.y = f2bf(v.y); o.z = f2bf(v.z); o.w = f2bf(v.w);
  *(ushort4*)(out + i) = o;
}

// ---------- V [b][k][d] fp32 -> VT [b][d][k] bf16 ----------
__global__ __launch_bounds__(256) void transpose_v(const float* __restrict__ V,
                                                   unsigned short* __restrict__ VT) {
  __shared__ float tile[32][33];
  int b = blockIdx.z;
  int d0 = blockIdx.x * 32, k0 = blockIdx.y * 32;
  const float* Vb = V + (size_t)b * S_ * D_;
  unsigned short* VTb = VT + (size_t)b * D_ * S_;
  int c = threadIdx.x & 31, r = threadIdx.x >> 5;
#pragma unroll
  for (int rr = 0; rr < 32; rr += 8)
    tile[r + rr][c] = Vb[(size_t)(k0 + r + rr) * D_ + d0 + c];
  __syncthreads();
#pragma unroll
  for (int rr = 0; rr < 32; rr += 8)
    VTb[(size_t)(d0 + r + rr) * S_ + k0 + c] = f2bf(tile[c][r + rr]);
}

// ---------- GEMM building blocks ----------
// R8: bodies reverted to R6 (R7's swizzle was an addressing no-op: with 64B rows
// and 16B slots, reachable banks are only {4t} ∪ {16+4t} — the 4.19e6
// "conflicts" are m134's intrinsic b128 cost (~12cyc vs 8 ideal), the HW floor.
// R7's transposed float4 epilogue also regressed (-6%); reverted.)
// New in R8: single-barrier double-buffered K-loop (catalog T3 minimum 2-phase):
// issue NEXT k-tile's global_load_lds BEFORE computing the current tile, one
// __syncthreads() per iter. The vmcnt(0) drain (inside syncthreads) then lands
// after ~400 cyc of ds_read+MFMA -> L2 staging latency (~200-300 cyc; Qb/Kb/VT
// are XCD-L2-resident) fully hidden, vs the old structure's per-iter exposed
// drain. Unrolled x2 for static buffer addressing.

__device__ __forceinline__ void stage4(const unsigned short* Ab, const unsigned short* Bb,
                                       int lda, int ldb, int k0, int srow, int scol,
                                       unsigned short* dA0, unsigned short* dA1,
                                       unsigned short* dB0, unsigned short* dB1) {
  load16(Ab + (size_t)srow * lda + k0 + scol, dA0);
  load16(Ab + (size_t)(srow + 64) * lda + k0 + scol, dA1);
  load16(Bb + (size_t)srow * ldb + k0 + scol, dB0);
  load16(Bb + (size_t)(srow + 64) * ldb + k0 + scol, dB1);
}

__device__ __forceinline__ void mfma_step(const unsigned short* sA, const unsigned short* sB,
                                          int mrow, int nrow, int l15, int quad,
                                          facc4 (&acc)[4][4]) {
  bfrag8 af[4], bq[4];
#pragma unroll
  for (int i = 0; i < 4; ++i)
    af[i] = *(const bfrag8*)(sA + (mrow + 16 * i + l15) * 32 + quad * 8);
#pragma unroll
  for (int j2 = 0; j2 < 4; ++j2)
    bq[j2] = *(const bfrag8*)(sB + (nrow + 16 * j2 + l15) * 32 + quad * 8);
#pragma unroll
  for (int i = 0; i < 4; ++i)
#pragma unroll
    for (int j2 = 0; j2 < 4; ++j2)
      acc[i][j2] = __builtin_amdgcn_mfma_f32_16x16x32_bf16(af[i], bq[j2], acc[i][j2], 0, 0, 0);
}

// gemm1 variant: grid (16,16,8); XCD swizzle — bz = j&7 so each batch pins to one
// XCD (Qb[b]+Kb[b] = 4 MB = one XCD L2); within XCD, by fastest.
__global__ __launch_bounds__(256) void gemm_qk(
    const unsigned short* __restrict__ A, int lda, long long astr,
    const unsigned short* __restrict__ Bm, int ldb, long long bstr,
    float* __restrict__ C, int ldc, long long cstr,
    int kdim, float scale) {
  const unsigned j = blockIdx.x + 16u * blockIdx.y + 256u * blockIdx.z;
  const unsigned bz = j & 7u;           // batch == XCD residue
  const unsigned q = j >> 3;            // [0,256)
  const unsigned by = q & 15u;          // m-tile
  const unsigned bx = q >> 4;           // n-tile [0,16)

  __shared__ unsigned short smA[2][128 * 32];
  __shared__ unsigned short smB[2][128 * 32];
  const int tid = threadIdx.x;
  const int wave = tid >> 6, lane = tid & 63;
  const int quad = lane >> 4, l15 = lane & 15;
  const unsigned short* Ab = A + (long long)bz * astr + (size_t)(by * 128) * lda;
  const unsigned short* Bb = Bm + (long long)bz * bstr + (size_t)(bx * 128) * ldb;
  const int srow = tid >> 2;          // staging row 0..63
  const int scol = (tid & 3) * 8;     // staging col (elements)
  const int so0 = wave * 512;         // staging dest, rows 0..63
  const int so1 = 2048 + wave * 512;  // staging dest, rows 64..127
  const int mrow = 64 * (wave >> 1);
  const int nrow = 64 * (wave & 1);

  facc4 acc[4][4];
  const facc4 fzero = {0.f, 0.f, 0.f, 0.f};
#pragma unroll
  for (int i = 0; i < 4; ++i)
#pragma unroll
    for (int j2 = 0; j2 < 4; ++j2) acc[i][j2] = fzero;

  // prologue: stage k-tile 0 into buffer 0 (exposed once)
  stage4(Ab, Bb, lda, ldb, 0, srow, scol,
         smA[0] + so0, smA[0] + so1, smB[0] + so0, smB[0] + so1);
  __syncthreads();

  // kdim is a multiple of 64 -> process 2 k-tiles per trip, static buffers
  for (int k0 = 0; k0 < kdim; k0 += 64) {
    stage4(Ab, Bb, lda, ldb, k0 + 32, srow, scol,
           smA[1] + so0, smA[1] + so1, smB[1] + so0, smB[1] + so1);
    mfma_step(smA[0], smB[0], mrow, nrow, l15, quad, acc);
    __syncthreads();
    if (k0 + 64 < kdim)
      stage4(Ab, Bb, lda, ldb, k0 + 64, srow, scol,
             smA[0] + so0, smA[0] + so1, smB[0] + so0, smB[0] + so1);
    mfma_step(smA[1], smB[1], mrow, nrow, l15, quad, acc);
    __syncthreads();
  }

  float* Cb = C + (long long)bz * cstr;
  const int mg = by * 128 + mrow;
  const int ng = bx * 128 + nrow;
#pragma unroll
  for (int i = 0; i < 4; ++i)
#pragma unroll
    for (int j2 = 0; j2 < 4; ++j2)
#pragma unroll
      for (int r = 0; r < 4; ++r)
        Cb[(size_t)(mg + 16 * i + quad * 4 + r) * ldc + ng + 16 * j2 + l15] = acc[i][j2][r] * scale;
}

// gemm2 variant: grid (4,16,8); bz = j&7 (batch pins to XCD, VT[b] 2 MB in L2);
// within XCD, bx fastest so the 4 n-blocks sharing one 512 KB attn A-tile run
// back-to-back on the same XCD (A fetched from HBM once).
__global__ __launch_bounds__(256) void gemm_pv(
    const unsigned short* __restrict__ A, int lda, long long astr,
    const unsigned short* __restrict__ Bm, int ldb, long long bstr,
    float* __restrict__ C, int ldc, long long cstr,
    int kdim, float scale) {
  const unsigned j = blockIdx.x + 4u * blockIdx.y + 64u * blockIdx.z;
  const unsigned bz = j & 7u;           // batch == XCD residue
  const unsigned q = j >> 3;            // [0,64)
  const unsigned bx = q & 3u;           // n-tile (fastest)
  const unsigned by = q >> 2;           // m-tile [0,16)

  __shared__ unsigned short smA[2][128 * 32];
  __shared__ unsigned short smB[2][128 * 32];
  const int tid = threadIdx.x;
  const int wave = tid >> 6, lane = tid & 63;
  const int quad = lane >> 4, l15 = lane & 15;
  const unsigned short* Ab = A + (long long)bz * astr + (size_t)(by * 128) * lda;
  const unsigned short* Bb = Bm + (long long)bz * bstr + (size_t)(bx * 128) * ldb;
  const int srow = tid >> 2;
  const int scol = (tid & 3) * 8;
  const int so0 = wave * 512;
  const int so1 = 2048 + wave * 512;
  const int mrow = 64 * (wave >> 1);
  const int nrow = 64 * (wave & 1);

  facc4 acc[4][4];
  const facc4 fzero = {0.f, 0.f, 0.f, 0.f};
#pragma unroll
  for (int i = 0; i < 4; ++i)
#pragma unroll
    for (int j2 = 0; j2 < 4; ++j2) acc[i][j2] = fzero;

  stage4(Ab, Bb, lda, ldb, 0, srow, scol,
         smA[0] + so0, smA[0] + so1, smB[0] + so0, smB[0] + so1);
  __syncthreads();

  for (int k0 = 0; k0 < kdim; k0 += 64) {
    stage4(Ab, Bb, lda, ldb, k0 + 32, srow, scol,
           smA[1] + so0, smA[1] + so1, smB[1] + so0, smB[1] + so1);
    mfma_step(smA[0], smB[0], mrow, nrow, l15, quad, acc);
    __syncthreads();
    if (k0 + 64 < kdim)
      stage4(Ab, Bb, lda, ldb, k0 + 64, srow, scol,
             smA[0] + so0, smA[0] + so1, smB[0] + so0, smB[0] + so1);
    mfma_step(smA[1], smB[1], mrow, nrow, l15, quad, acc);
    __syncthreads();
  }

  float* Cb = C + (long long)bz * cstr;
  const int mg = by * 128 + mrow;
  const int ng = bx * 128 + nrow;
#pragma unroll
  for (int i = 0; i < 4; ++i)
#pragma unroll
    for (int j2 = 0; j2 < 4; ++j2)
#pragma unroll
      for (int r = 0; r < 4; ++r)
        Cb[(size_t)(mg + 16 * i + quad * 4 + r) * ldc + ng + 16 * j2 + l15] = acc[i][j2][r] * scale;
}

// ---------- 256-bin radix-select step (per-wave histogram already counted) ----------
// bins[256]: counts. Finds digit d* s.t. count(digit > d*) < krem <= count(digit >= d*).
// Returns d*; *krem_out = krem - count(digit > d*)  (rank within the d* bin).
// If no crossing exists (total count < krem), returns 0 with *krem_out = 0.
__device__ __forceinline__ unsigned sel256(const unsigned* bins, int lane,
                                           unsigned krem, unsigned* krem_out) {
  const uint4 b = *(const uint4*)(bins + lane * 4);
  const unsigned s = b.x + b.y + b.z + b.w;
  unsigned t = s;
#pragma unroll
  for (int off = 1; off < 64; off <<= 1) {
    unsigned u = (unsigned)__shfl_down((int)t, off);
    t += (lane + off < 64) ? u : 0u;
  }
  const unsigned texcl = t - s;           // suffix over lanes > lane
  const unsigned c3 = texcl + b.w;        // count(digit >= lane*4+3)
  const unsigned c2 = c3 + b.z;
  const unsigned c1 = c2 + b.y;
  const unsigned c0 = c1 + b.x;
  unsigned pack = 0;                      // nonzero in at most one lane
  if (c0 >= krem && c1 < krem)    pack = ((krem - c1) << 8) | (lane * 4 + 0);
  if (c1 >= krem && c2 < krem)    pack = ((krem - c2) << 8) | (lane * 4 + 1);
  if (c2 >= krem && c3 < krem)    pack = ((krem - c3) << 8) | (lane * 4 + 2);
  if (c3 >= krem && texcl < krem) pack = ((krem - texcl) << 8) | (lane * 4 + 3);
#pragma unroll
  for (int off = 1; off < 64; off <<= 1)
    pack |= (unsigned)__shfl_xor((int)pack, off);
  *krem_out = pack >> 8;
  return pack & 255u;
}

// ---------- per-row exact top-204 + softmax-of-sparse; one WAVE per row ----------
// R6 (kept verbatim — proven: conflicts gone, ~44us): quantile-digit select,
// losers not counted. Pass-1 digit t=(key>>16)-0xBF00 counts only t in [1,255];
// scores < ~0.5 can't be top-204 when >=204 elements have t>=1 (N(0,1): ~632).
// d1 in [1,254] pins the key's top 16 bits; 2 more 8-bit passes finish. Any
// degenerate case (d1==0 no-crossing, or clamp-top d1==255) -> full exact
// 4-pass radix fallback (wave-uniform, never taken for this data).
__global__ __launch_bounds__(256) void topk_softmax(float* __restrict__ scores) {
  __shared__ unsigned binsAll[4][256];    // 1KB per wave
  const int tid = threadIdx.x;
  const int wave = tid >> 6, lane = tid & 63;
  const long long row = (long long)blockIdx.x * 4 + wave;
  float* srow = scores + row * 2048;
  unsigned* bins = binsAll[wave];

  unsigned k[32];
#pragma unroll
  for (int c = 0; c < 4; ++c) {
    float4 a = *(const float4*)(srow + c * 512 + lane * 8);
    float4 b = *(const float4*)(srow + c * 512 + lane * 8 + 4);
    k[c * 8 + 0] = fkey(a.x); k[c * 8 + 1] = fkey(a.y);
    k[c * 8 + 2] = fkey(a.z); k[c * 8 + 3] = fkey(a.w);
    k[c * 8 + 4] = fkey(b.x); k[c * 8 + 5] = fkey(b.y);
    k[c * 8 + 6] = fkey(b.z); k[c * 8 + 7] = fkey(b.w);
  }

  // row max (for softmax shift m = max(max_score, 0))
  unsigned kmax = 0;
#pragma unroll
  for (int i = 0; i < 32; ++i) kmax = max(kmax, k[i]);
#pragma unroll
  for (int off = 1; off < 64; off <<= 1)
    kmax = max(kmax, (unsigned)__shfl_xor((int)kmax, off));
  const float m = fmaxf(keyfloat(kmax), 0.f);

  // ---- pass 1: quantile digit t = (key>>16) - 0xBF00; count only t in [1,255] ----
  {
    uint4 z; z.x = 0; z.y = 0; z.z = 0; z.w = 0;
    *(uint4*)(bins + lane * 4) = z;
  }
#pragma unroll
  for (int i = 0; i < 32; ++i) {
    const int t = (int)(k[i] >> 16) - 0xBF00;
    if (t >= 1) atomicAdd(&bins[min(t, 255)], 1u);
  }
  unsigned krem;
  const unsigned d1 = sel256(bins, lane, KTOP, &krem);

  unsigned tkey;
  if (d1 >= 1u && d1 <= 254u) {
    // common path: key's top 16 bits are exactly 0xBF00+d1 (unclamped digit)
    const unsigned top16 = 0xBF00u + d1;
    // ---- pass 2: bits[15:8] among class (key>>16)==top16 ----
    { uint4 z; z.x = 0; z.y = 0; z.z = 0; z.w = 0; *(uint4*)(bins + lane * 4) = z; }
#pragma unroll
    for (int i = 0; i < 32; ++i)
      if ((k[i] >> 16) == top16) atomicAdd(&bins[(k[i] >> 8) & 255u], 1u);
    const unsigned b1 = sel256(bins, lane, krem, &krem);
    const unsigned top24 = (top16 << 8) | b1;
    // ---- pass 3: bits[7:0] among class (key>>8)==top24 ----
    { uint4 z; z.x = 0; z.y = 0; z.z = 0; z.w = 0; *(uint4*)(bins + lane * 4) = z; }
#pragma unroll
    for (int i = 0; i < 32; ++i)
      if ((k[i] >> 8) == top24) atomicAdd(&bins[k[i] & 255u], 1u);
    const unsigned b0 = sel256(bins, lane, krem, &krem);
    tkey = (top24 << 8) | b0;
  } else {
    // fallback: full exact 4-pass 8-bit radix from scratch. Never taken here.
    krem = KTOP;
    unsigned prefix = 0, mmask = 0;
    for (int shift = 24; shift >= 0; shift -= 8) {
      { uint4 z; z.x = 0; z.y = 0; z.z = 0; z.w = 0; *(uint4*)(bins + lane * 4) = z; }
#pragma unroll
      for (int i = 0; i < 32; ++i)
        if ((k[i] & mmask) == prefix) atomicAdd(&bins[(k[i] >> shift) & 255u], 1u);
      const unsigned dig = sel256(bins, lane, krem, &krem);
      prefix |= dig << shift;
      mmask |= 0xFFu << shift;
    }
    tkey = prefix;
  }

  // tie-break: accept the krem lowest-index elements with key == tkey.
  // cut = global index of the last accepted tie.
  unsigned cut;
  {
    unsigned tiem = 0;
#pragma unroll
    for (int i = 0; i < 32; ++i)
      if (k[i] == tkey) tiem |= 1u << i;
    unsigned need = krem;
    for (;;) {
      unsigned myidx = 0xFFFFFFFFu;
      if (tiem) {
        int i = __ffs((int)tiem) - 1;       // lowest i = smallest global idx in lane
        myidx = ((unsigned)(i >> 3)) * 512u + (unsigned)lane * 8u + (unsigned)(i & 7);
      }
      unsigned minidx = myidx;
#pragma unroll
      for (int off = 1; off < 64; off <<= 1)
        minidx = min(minidx, (unsigned)__shfl_xor((int)minidx, off));
      if (--need == 0 || minidx == 0xFFFFFFFFu) { cut = minidx; break; }
      if (myidx == minidx) tiem &= tiem - 1; // consume in owning lane
    }
  }

  // weights: exp(s-m) if selected, exp(-m) otherwise; Z = sum of all weights
  const float eqw = __expf(keyfloat(tkey) - m);
  const float base = __expf(-m);
  float zsum = 0.f;
#pragma unroll
  for (int i = 0; i < 32; ++i) {
    const unsigned key = k[i];
    const unsigned idx = ((unsigned)(i >> 3)) * 512u + (unsigned)lane * 8u + (unsigned)(i & 7);
    float w;
    if (key > tkey) w = __expf(keyfloat(key) - m);
    else w = (key == tkey && idx <= cut) ? eqw : base;
    zsum += w;
    k[i] = __float_as_uint(w);              // stash unnormalized weight
  }
#pragma unroll
  for (int off = 1; off < 64; off <<= 1) zsum += __shfl_xor(zsum, off);
  const float invZ = 1.f / zsum;

  // attn row (bf16) reuses the front 4KB of this row's 8KB score slot
  unsigned short* arow = (unsigned short*)scores + row * 4096;
#pragma unroll
  for (int c = 0; c < 4; ++c) {
    union { unsigned short u[8]; int4 v4; } pk;
#pragma unroll
    for (int j = 0; j < 8; ++j)
      pk.u[j] = f2bf(__uint_as_float(k[c * 8 + j]) * invZ);
    *(int4*)(arow + c * 512 + lane * 8) = pk.v4;
  }
}

// ---------- launch ----------
// ws layout (bytes): Qb[0,16MB) Kb[16,32MB) VT[32,48MB) scores/attn[48,176MB)
extern "C" void kernel_launch(void* const* d_in, const int* in_sizes, int n_in,
                              void* d_out, int out_size, void* d_ws, size_t ws_size,
                              hipStream_t stream) {
  const float* Q = (const float*)d_in[0];
  const float* K = (const float*)d_in[1];
  const float* V = (const float*)d_in[2];
  float* out = (float*)d_out;
  char* ws = (char*)d_ws;
  unsigned short* Qb = (unsigned short*)(ws);
  unsigned short* Kb = (unsigned short*)(ws + ((size_t)16 << 20));
  unsigned short* VT = (unsigned short*)(ws + ((size_t)32 << 20));
  float* scores = (float*)(ws + ((size_t)48 << 20));

  const int nel = B_ * S_ * D_;  // 8388608
  cvt_qk<<<dim3(nel / 1024, 2), 256, 0, stream>>>(Q, K, Qb, Kb);
  transpose_v<<<dim3(D_ / 32, S_ / 32, B_), 256, 0, stream>>>(V, VT);
  // scores[b][q][k] = sum_d Q[q][d]*K[k][d] * scale ; score row pitch = 2048 f32
  gemm_qk<<<dim3(S_ / 128, S_ / 128, B_), 256, 0, stream>>>(
      Qb, D_, (long long)S_ * D_, Kb, D_, (long long)S_ * D_,
      scores, S_, (long long)S_ * S_, D_, QK_SCALE);
  topk_softmax<<<B_ * S_ / 4, 256, 0, stream>>>(scores);
  // out[b][q][d] = sum_k attn[q][k]*VT[d][k] ; attn row pitch = 4096 bf16 (8KB slots)
  gemm_pv<<<dim3(D_ / 128, S_ / 128, B_), 256, 0, stream>>>(
      (const unsigned short*)scores, 4096, (long long)S_ * 4096,
      VT, S_, (long long)D_ * S_, out, D_, (long long)S_ * D_, S_, 1.0f);
}

// Round 8
// 270.806 us; speedup vs baseline: 1.0663x; 1.0562x over previous
//
#include <hip/hip_runtime.h>
#include <math.h>

// Problem constants (B=8, S=2048, D=512)
#define B_ 8
#define S_ 2048
#define D_ 512
#define KTOP 204                      // int(2048*0.1)
#define QK_SCALE 0.044194173824159216f // 1/sqrt(512)

typedef short bfrag8 __attribute__((ext_vector_type(8)));  // 8 bf16 (4 VGPRs)
typedef float facc4 __attribute__((ext_vector_type(4)));   // MFMA accumulator

// ---------- helpers ----------
__device__ __forceinline__ unsigned short f2bf(float f) {
  unsigned u = __float_as_uint(f);
  u += 0x7FFFu + ((u >> 16) & 1);   // RNE
  return (unsigned short)(u >> 16);
}

// order-preserving map: descending float order == descending uint order
__device__ __forceinline__ unsigned fkey(float f) {
  unsigned b = __float_as_uint(f);
  return (b & 0x80000000u) ? ~b : (b | 0x80000000u);
}
__device__ __forceinline__ float keyfloat(unsigned k) {
  unsigned b = (k & 0x80000000u) ? (k & 0x7FFFFFFFu) : ~k;
  return __uint_as_float(b);
}

__device__ __forceinline__ void load16(const unsigned short* g, unsigned short* l) {
  __builtin_amdgcn_global_load_lds(
      (const __attribute__((address_space(1))) void*)g,
      (__attribute__((address_space(3))) void*)l, 16, 0, 0);
}

// ---------- fp32 -> bf16 convert, Q and K in one launch ----------
__global__ __launch_bounds__(256) void cvt_qk(const float* __restrict__ Q,
                                              const float* __restrict__ K,
                                              unsigned short* __restrict__ Qb,
                                              unsigned short* __restrict__ Kb) {
  const float* in = blockIdx.y ? K : Q;
  unsigned short* out = blockIdx.y ? Kb : Qb;
  int i = (blockIdx.x * 256 + threadIdx.x) * 4;
  float4 v = *(const float4*)(in + i);
  ushort4 o;
  o.x = f2bf(v.x); o.y = f2bf(v.y); o.z = f2bf(v.z); o.w = f2bf(v.w);
  *(ushort4*)(out + i) = o;
}

// ---------- V [b][k][d] fp32 -> VT [b][d][k] bf16 ----------
__global__ __launch_bounds__(256) void transpose_v(const float* __restrict__ V,
                                                   unsigned short* __restrict__ VT) {
  __shared__ float tile[32][33];
  int b = blockIdx.z;
  int d0 = blockIdx.x * 32, k0 = blockIdx.y * 32;
  const float* Vb = V + (size_t)b * S_ * D_;
  unsigned short* VTb = VT + (size_t)b * D_ * S_;
  int c = threadIdx.x & 31, r = threadIdx.x >> 5;
#pragma unroll
  for (int rr = 0; rr < 32; rr += 8)
    tile[r + rr][c] = Vb[(size_t)(k0 + r + rr) * D_ + d0 + c];
  __syncthreads();
#pragma unroll
  for (int rr = 0; rr < 32; rr += 8)
    VTb[(size_t)(d0 + r + rr) * S_ + k0 + c] = f2bf(tile[c][r + rr]);
}

// ---------- GEMM building blocks ----------
// R9: BK=64 double-buffered (8 phases for qk instead of 16; 16 for pv instead
// of 32 — halves the m233-style per-phase stage+vmcnt+barrier overhead) with a
// true T2 XOR swizzle. At BK=32 (4 slots/row) a swizzle can't spread banks
// (R7 lesson); at BK=64 (8 x 16B slots/row) it reaches all 32 banks.
// Both-sides-or-neither (rule #21): global SOURCE chunk is pre-swizzled
// ((l&7)^(row&7)), LDS dest stays linear (global_load_lds writes base+lane*16),
// ds_read slot applies the same involution ((c*4+quad)^(l15&7)).
// LDS image: buf[row][64] row-major, 128B rows; LDS[r][slot] = global chunk
// slot^(r&7). Unswizzled BK=64 would be a 16-way read conflict; swizzled ~2-way
// (free, m136).

// stage one 128x64 k-tile of matrix M into LDS buffer dst (wave-uniform base).
// 4 sweeps of 32 rows; lane l covers row (tid>>3), chunk (l&7) pre-swizzled.
__device__ __forceinline__ void stage64(const unsigned short* M, int ld, int k0,
                                        int tid, unsigned short* dst) {
  const int wave = tid >> 6;
  const int row = tid >> 3;                              // 0..31 per sweep
  const int col = ((tid & 7) ^ (row & 7)) * 8;           // swizzled source chunk
  unsigned short* wdst = dst + wave * 512;               // 1KB per wave per sweep
  const unsigned short* src = M + (size_t)row * ld + k0 + col;
#pragma unroll
  for (int s = 0; s < 4; ++s)
    load16(src + (size_t)(s * 32) * ld, wdst + s * 2048);
}

// 32 MFMAs over one 128x64 x 128x64 LDS tile pair (2 k-chunks of 32).
__device__ __forceinline__ void mfma_step64(const unsigned short* sA, const unsigned short* sB,
                                            int mrow, int nrow, int l15, int quad,
                                            facc4 (&acc)[4][4]) {
#pragma unroll
  for (int c = 0; c < 2; ++c) {
    const int slot = ((c * 4 + quad) ^ (l15 & 7)) * 8;   // swizzled read slot
    bfrag8 af[4], bq[4];
#pragma unroll
    for (int i = 0; i < 4; ++i)
      af[i] = *(const bfrag8*)(sA + (mrow + 16 * i + l15) * 64 + slot);
#pragma unroll
    for (int j2 = 0; j2 < 4; ++j2)
      bq[j2] = *(const bfrag8*)(sB + (nrow + 16 * j2 + l15) * 64 + slot);
#pragma unroll
    for (int i = 0; i < 4; ++i)
#pragma unroll
      for (int j2 = 0; j2 < 4; ++j2)
        acc[i][j2] = __builtin_amdgcn_mfma_f32_16x16x32_bf16(af[i], bq[j2], acc[i][j2], 0, 0, 0);
  }
}

// gemm1 variant: grid (16,16,8); XCD swizzle — bz = j&7 so each batch pins to one
// XCD (Qb[b]+Kb[b] = 4 MB = one XCD L2); within XCD, by fastest.
__global__ __launch_bounds__(256) void gemm_qk(
    const unsigned short* __restrict__ A, int lda, long long astr,
    const unsigned short* __restrict__ Bm, int ldb, long long bstr,
    float* __restrict__ C, int ldc, long long cstr,
    int kdim, float scale) {
  const unsigned j = blockIdx.x + 16u * blockIdx.y + 256u * blockIdx.z;
  const unsigned bz = j & 7u;           // batch == XCD residue
  const unsigned q = j >> 3;            // [0,256)
  const unsigned by = q & 15u;          // m-tile
  const unsigned bx = q >> 4;           // n-tile [0,16)

  __shared__ unsigned short smA[2][128 * 64];
  __shared__ unsigned short smB[2][128 * 64];
  const int tid = threadIdx.x;
  const int wave = tid >> 6, lane = tid & 63;
  const int quad = lane >> 4, l15 = lane & 15;
  const unsigned short* Ab = A + (long long)bz * astr + (size_t)(by * 128) * lda;
  const unsigned short* Bb = Bm + (long long)bz * bstr + (size_t)(bx * 128) * ldb;
  const int mrow = 64 * (wave >> 1);
  const int nrow = 64 * (wave & 1);

  facc4 acc[4][4];
  const facc4 fzero = {0.f, 0.f, 0.f, 0.f};
#pragma unroll
  for (int i = 0; i < 4; ++i)
#pragma unroll
    for (int j2 = 0; j2 < 4; ++j2) acc[i][j2] = fzero;

  // prologue: stage k-tile 0 into buffer 0 (exposed once)
  stage64(Ab, lda, 0, tid, smA[0]);
  stage64(Bb, ldb, 0, tid, smB[0]);
  __syncthreads();

  // kdim is a multiple of 128 -> 2 k-tiles of 64 per trip, static buffers
  for (int k0 = 0; k0 < kdim; k0 += 128) {
    stage64(Ab, lda, k0 + 64, tid, smA[1]);
    stage64(Bb, ldb, k0 + 64, tid, smB[1]);
    mfma_step64(smA[0], smB[0], mrow, nrow, l15, quad, acc);
    __syncthreads();
    if (k0 + 128 < kdim) {
      stage64(Ab, lda, k0 + 128, tid, smA[0]);
      stage64(Bb, ldb, k0 + 128, tid, smB[0]);
    }
    mfma_step64(smA[1], smB[1], mrow, nrow, l15, quad, acc);
    __syncthreads();
  }

  float* Cb = C + (long long)bz * cstr;
  const int mg = by * 128 + mrow;
  const int ng = bx * 128 + nrow;
#pragma unroll
  for (int i = 0; i < 4; ++i)
#pragma unroll
    for (int j2 = 0; j2 < 4; ++j2)
#pragma unroll
      for (int r = 0; r < 4; ++r)
        Cb[(size_t)(mg + 16 * i + quad * 4 + r) * ldc + ng + 16 * j2 + l15] = acc[i][j2][r] * scale;
}

// gemm2 variant: grid (4,16,8); bz = j&7 (batch pins to XCD, VT[b] 2 MB in L2);
// within XCD, bx fastest so the 4 n-blocks sharing one 512 KB attn A-tile run
// back-to-back on the same XCD (A fetched from HBM once).
__global__ __launch_bounds__(256) void gemm_pv(
    const unsigned short* __restrict__ A, int lda, long long astr,
    const unsigned short* __restrict__ Bm, int ldb, long long bstr,
    float* __restrict__ C, int ldc, long long cstr,
    int kdim, float scale) {
  const unsigned j = blockIdx.x + 4u * blockIdx.y + 64u * blockIdx.z;
  const unsigned bz = j & 7u;           // batch == XCD residue
  const unsigned q = j >> 3;            // [0,64)
  const unsigned bx = q & 3u;           // n-tile (fastest)
  const unsigned by = q >> 2;           // m-tile [0,16)

  __shared__ unsigned short smA[2][128 * 64];
  __shared__ unsigned short smB[2][128 * 64];
  const int tid = threadIdx.x;
  const int wave = tid >> 6, lane = tid & 63;
  const int quad = lane >> 4, l15 = lane & 15;
  const unsigned short* Ab = A + (long long)bz * astr + (size_t)(by * 128) * lda;
  const unsigned short* Bb = Bm + (long long)bz * bstr + (size_t)(bx * 128) * ldb;
  const int mrow = 64 * (wave >> 1);
  const int nrow = 64 * (wave & 1);

  facc4 acc[4][4];
  const facc4 fzero = {0.f, 0.f, 0.f, 0.f};
#pragma unroll
  for (int i = 0; i < 4; ++i)
#pragma unroll
    for (int j2 = 0; j2 < 4; ++j2) acc[i][j2] = fzero;

  stage64(Ab, lda, 0, tid, smA[0]);
  stage64(Bb, ldb, 0, tid, smB[0]);
  __syncthreads();

  for (int k0 = 0; k0 < kdim; k0 += 128) {
    stage64(Ab, lda, k0 + 64, tid, smA[1]);
    stage64(Bb, ldb, k0 + 64, tid, smB[1]);
    mfma_step64(smA[0], smB[0], mrow, nrow, l15, quad, acc);
    __syncthreads();
    if (k0 + 128 < kdim) {
      stage64(Ab, lda, k0 + 128, tid, smA[0]);
      stage64(Bb, ldb, k0 + 128, tid, smB[0]);
    }
    mfma_step64(smA[1], smB[1], mrow, nrow, l15, quad, acc);
    __syncthreads();
  }

  float* Cb = C + (long long)bz * cstr;
  const int mg = by * 128 + mrow;
  const int ng = bx * 128 + nrow;
#pragma unroll
  for (int i = 0; i < 4; ++i)
#pragma unroll
    for (int j2 = 0; j2 < 4; ++j2)
#pragma unroll
      for (int r = 0; r < 4; ++r)
        Cb[(size_t)(mg + 16 * i + quad * 4 + r) * ldc + ng + 16 * j2 + l15] = acc[i][j2][r] * scale;
}

// ---------- 256-bin radix-select step (per-wave histogram already counted) ----------
// bins[256]: counts. Finds digit d* s.t. count(digit > d*) < krem <= count(digit >= d*).
// Returns d*; *krem_out = krem - count(digit > d*)  (rank within the d* bin).
// If no crossing exists (total count < krem), returns 0 with *krem_out = 0.
__device__ __forceinline__ unsigned sel256(const unsigned* bins, int lane,
                                           unsigned krem, unsigned* krem_out) {
  const uint4 b = *(const uint4*)(bins + lane * 4);
  const unsigned s = b.x + b.y + b.z + b.w;
  unsigned t = s;
#pragma unroll
  for (int off = 1; off < 64; off <<= 1) {
    unsigned u = (unsigned)__shfl_down((int)t, off);
    t += (lane + off < 64) ? u : 0u;
  }
  const unsigned texcl = t - s;           // suffix over lanes > lane
  const unsigned c3 = texcl + b.w;        // count(digit >= lane*4+3)
  const unsigned c2 = c3 + b.z;
  const unsigned c1 = c2 + b.y;
  const unsigned c0 = c1 + b.x;
  unsigned pack = 0;                      // nonzero in at most one lane
  if (c0 >= krem && c1 < krem)    pack = ((krem - c1) << 8) | (lane * 4 + 0);
  if (c1 >= krem && c2 < krem)    pack = ((krem - c2) << 8) | (lane * 4 + 1);
  if (c2 >= krem && c3 < krem)    pack = ((krem - c3) << 8) | (lane * 4 + 2);
  if (c3 >= krem && texcl < krem) pack = ((krem - texcl) << 8) | (lane * 4 + 3);
#pragma unroll
  for (int off = 1; off < 64; off <<= 1)
    pack |= (unsigned)__shfl_xor((int)pack, off);
  *krem_out = pack >> 8;
  return pack & 255u;
}

// ---------- per-row exact top-204 + softmax-of-sparse; one WAVE per row ----------
// R6 (kept verbatim — proven: conflicts gone, ~44us): quantile-digit select,
// losers not counted. Pass-1 digit t=(key>>16)-0xBF00 counts only t in [1,255];
// scores < ~0.5 can't be top-204 when >=204 elements have t>=1 (N(0,1): ~632).
// d1 in [1,254] pins the key's top 16 bits; 2 more 8-bit passes finish. Any
// degenerate case (d1==0 no-crossing, or clamp-top d1==255) -> full exact
// 4-pass radix fallback (wave-uniform, never taken for this data).
__global__ __launch_bounds__(256) void topk_softmax(float* __restrict__ scores) {
  __shared__ unsigned binsAll[4][256];    // 1KB per wave
  const int tid = threadIdx.x;
  const int wave = tid >> 6, lane = tid & 63;
  const long long row = (long long)blockIdx.x * 4 + wave;
  float* srow = scores + row * 2048;
  unsigned* bins = binsAll[wave];

  unsigned k[32];
#pragma unroll
  for (int c = 0; c < 4; ++c) {
    float4 a = *(const float4*)(srow + c * 512 + lane * 8);
    float4 b = *(const float4*)(srow + c * 512 + lane * 8 + 4);
    k[c * 8 + 0] = fkey(a.x); k[c * 8 + 1] = fkey(a.y);
    k[c * 8 + 2] = fkey(a.z); k[c * 8 + 3] = fkey(a.w);
    k[c * 8 + 4] = fkey(b.x); k[c * 8 + 5] = fkey(b.y);
    k[c * 8 + 6] = fkey(b.z); k[c * 8 + 7] = fkey(b.w);
  }

  // row max (for softmax shift m = max(max_score, 0))
  unsigned kmax = 0;
#pragma unroll
  for (int i = 0; i < 32; ++i) kmax = max(kmax, k[i]);
#pragma unroll
  for (int off = 1; off < 64; off <<= 1)
    kmax = max(kmax, (unsigned)__shfl_xor((int)kmax, off));
  const float m = fmaxf(keyfloat(kmax), 0.f);

  // ---- pass 1: quantile digit t = (key>>16) - 0xBF00; count only t in [1,255] ----
  {
    uint4 z; z.x = 0; z.y = 0; z.z = 0; z.w = 0;
    *(uint4*)(bins + lane * 4) = z;
  }
#pragma unroll
  for (int i = 0; i < 32; ++i) {
    const int t = (int)(k[i] >> 16) - 0xBF00;
    if (t >= 1) atomicAdd(&bins[min(t, 255)], 1u);
  }
  unsigned krem;
  const unsigned d1 = sel256(bins, lane, KTOP, &krem);

  unsigned tkey;
  if (d1 >= 1u && d1 <= 254u) {
    // common path: key's top 16 bits are exactly 0xBF00+d1 (unclamped digit)
    const unsigned top16 = 0xBF00u + d1;
    // ---- pass 2: bits[15:8] among class (key>>16)==top16 ----
    { uint4 z; z.x = 0; z.y = 0; z.z = 0; z.w = 0; *(uint4*)(bins + lane * 4) = z; }
#pragma unroll
    for (int i = 0; i < 32; ++i)
      if ((k[i] >> 16) == top16) atomicAdd(&bins[(k[i] >> 8) & 255u], 1u);
    const unsigned b1 = sel256(bins, lane, krem, &krem);
    const unsigned top24 = (top16 << 8) | b1;
    // ---- pass 3: bits[7:0] among class (key>>8)==top24 ----
    { uint4 z; z.x = 0; z.y = 0; z.z = 0; z.w = 0; *(uint4*)(bins + lane * 4) = z; }
#pragma unroll
    for (int i = 0; i < 32; ++i)
      if ((k[i] >> 8) == top24) atomicAdd(&bins[k[i] & 255u], 1u);
    const unsigned b0 = sel256(bins, lane, krem, &krem);
    tkey = (top24 << 8) | b0;
  } else {
    // fallback: full exact 4-pass 8-bit radix from scratch. Never taken here.
    krem = KTOP;
    unsigned prefix = 0, mmask = 0;
    for (int shift = 24; shift >= 0; shift -= 8) {
      { uint4 z; z.x = 0; z.y = 0; z.z = 0; z.w = 0; *(uint4*)(bins + lane * 4) = z; }
#pragma unroll
      for (int i = 0; i < 32; ++i)
        if ((k[i] & mmask) == prefix) atomicAdd(&bins[(k[i] >> shift) & 255u], 1u);
      const unsigned dig = sel256(bins, lane, krem, &krem);
      prefix |= dig << shift;
      mmask |= 0xFFu << shift;
    }
    tkey = prefix;
  }

  // tie-break: accept the krem lowest-index elements with key == tkey.
  // cut = global index of the last accepted tie.
  unsigned cut;
  {
    unsigned tiem = 0;
#pragma unroll
    for (int i = 0; i < 32; ++i)
      if (k[i] == tkey) tiem |= 1u << i;
    unsigned need = krem;
    for (;;) {
      unsigned myidx = 0xFFFFFFFFu;
      if (tiem) {
        int i = __ffs((int)tiem) - 1;       // lowest i = smallest global idx in lane
        myidx = ((unsigned)(i >> 3)) * 512u + (unsigned)lane * 8u + (unsigned)(i & 7);
      }
      unsigned minidx = myidx;
#pragma unroll
      for (int off = 1; off < 64; off <<= 1)
        minidx = min(minidx, (unsigned)__shfl_xor((int)minidx, off));
      if (--need == 0 || minidx == 0xFFFFFFFFu) { cut = minidx; break; }
      if (myidx == minidx) tiem &= tiem - 1; // consume in owning lane
    }
  }

  // weights: exp(s-m) if selected, exp(-m) otherwise; Z = sum of all weights
  const float eqw = __expf(keyfloat(tkey) - m);
  const float base = __expf(-m);
  float zsum = 0.f;
#pragma unroll
  for (int i = 0; i < 32; ++i) {
    const unsigned key = k[i];
    const unsigned idx = ((unsigned)(i >> 3)) * 512u + (unsigned)lane * 8u + (unsigned)(i & 7);
    float w;
    if (key > tkey) w = __expf(keyfloat(key) - m);
    else w = (key == tkey && idx <= cut) ? eqw : base;
    zsum += w;
    k[i] = __float_as_uint(w);              // stash unnormalized weight
  }
#pragma unroll
  for (int off = 1; off < 64; off <<= 1) zsum += __shfl_xor(zsum, off);
  const float invZ = 1.f / zsum;

  // attn row (bf16) reuses the front 4KB of this row's 8KB score slot
  unsigned short* arow = (unsigned short*)scores + row * 4096;
#pragma unroll
  for (int c = 0; c < 4; ++c) {
    union { unsigned short u[8]; int4 v4; } pk;
#pragma unroll
    for (int j = 0; j < 8; ++j)
      pk.u[j] = f2bf(__uint_as_float(k[c * 8 + j]) * invZ);
    *(int4*)(arow + c * 512 + lane * 8) = pk.v4;
  }
}

// ---------- launch ----------
// ws layout (bytes): Qb[0,16MB) Kb[16,32MB) VT[32,48MB) scores/attn[48,176MB)
extern "C" void kernel_launch(void* const* d_in, const int* in_sizes, int n_in,
                              void* d_out, int out_size, void* d_ws, size_t ws_size,
                              hipStream_t stream) {
  const float* Q = (const float*)d_in[0];
  const float* K = (const float*)d_in[1];
  const float* V = (const float*)d_in[2];
  float* out = (float*)d_out;
  char* ws = (char*)d_ws;
  unsigned short* Qb = (unsigned short*)(ws);
  unsigned short* Kb = (unsigned short*)(ws + ((size_t)16 << 20));
  unsigned short* VT = (unsigned short*)(ws + ((size_t)32 << 20));
  float* scores = (float*)(ws + ((size_t)48 << 20));

  const int nel = B_ * S_ * D_;  // 8388608
  cvt_qk<<<dim3(nel / 1024, 2), 256, 0, stream>>>(Q, K, Qb, Kb);
  transpose_v<<<dim3(D_ / 32, S_ / 32, B_), 256, 0, stream>>>(V, VT);
  // scores[b][q][k] = sum_d Q[q][d]*K[k][d] * scale ; score row pitch = 2048 f32
  gemm_qk<<<dim3(S_ / 128, S_ / 128, B_), 256, 0, stream>>>(
      Qb, D_, (long long)S_ * D_, Kb, D_, (long long)S_ * D_,
      scores, S_, (long long)S_ * S_, D_, QK_SCALE);
  topk_softmax<<<B_ * S_ / 4, 256, 0, stream>>>(scores);
  // out[b][q][d] = sum_k attn[q][k]*VT[d][k] ; attn row pitch = 4096 bf16 (8KB slots)
  gemm_pv<<<dim3(D_ / 128, S_ / 128, B_), 256, 0, stream>>>(
      (const unsigned short*)scores, 4096, (long long)S_ * 4096,
      VT, S_, (long long)D_ * S_, out, D_, (long long)S_ * D_, S_, 1.0f);
}